// Round 8
// baseline (2068.711 us; speedup 1.0000x reference)
//
#include <hip/hip_runtime.h>
#include <hip/hip_bf16.h>

#define BS 64
#define SEQ 200
#define NSK 4096
#define DS 256
#define SM 64
#define NROWS (BS*SEQ)
#define FP8_VG 26                        // weight frags in VGPR per wave
#define FP8_LDS 38                       // weight frags in LDS per wave
#define LSTM_LDS (4096 + FP8_LDS*8*512)  // 4KB h + 155648B weights = 159744

typedef __attribute__((ext_vector_type(8))) short bf16x8;
typedef __attribute__((ext_vector_type(4))) float f32x4;
typedef unsigned long long u64;

__device__ __forceinline__ float sigf(float x){ return 1.0f/(1.0f+expf(-x)); }
__device__ __forceinline__ float fast_sig(float x){ return 1.0f/(1.0f+__expf(-x)); }
__device__ __forceinline__ float fast_tanh(float x){
  float t = __expf(-2.0f*fabsf(x));
  float r = (1.0f - t)/(1.0f + t);
  return copysignf(r, x);
}
__device__ __forceinline__ short f2bf(float x){
  unsigned int u = __float_as_uint(x);
  unsigned int r = (u + 0x7fffu + ((u >> 16) & 1u)) >> 16;
  return (short)r;
}
__device__ __forceinline__ float bf2f(unsigned short s){
  return __uint_as_float(((unsigned int)s) << 16);
}
// f32 -> OCP e4m3fn, RNE (values here are small; clamp only for safety)
__device__ __forceinline__ unsigned int f2e4m3(float x){
  unsigned int u = __float_as_uint(x);
  unsigned int s = (u >> 24) & 0x80u;
  unsigned int eb = (u >> 23) & 0xffu;
  unsigned int m = u & 0x7fffffu;
  if (eb == 0) return s;                       // f32 zero/denorm -> 0
  int e = (int)eb - 127;
  if (e >= -6){
    unsigned int lsb = (m >> 20) & 1u;
    unsigned int r = (m + 0x7ffffu + lsb) >> 20;   // 3-bit mantissa (may carry to 8)
    unsigned int ee = (unsigned int)(e + 7);
    if (r == 8u){ r = 0u; ee += 1u; }
    if (ee > 15u || (ee == 15u && r > 6u)){ ee = 15u; r = 6u; }   // clamp 448
    return s | (ee << 3) | r;
  } else {
    int shift = 14 - e;                          // >= 21
    if (shift > 31) return s;
    unsigned int full = 0x800000u | m;
    unsigned int keep = full >> shift;
    unsigned int rem  = full & ((1u << shift) - 1u);
    unsigned int half = 1u << (shift - 1);
    if (rem > half || (rem == half && (keep & 1u))) keep++;
    if (keep >= 8u) return s | (1u << 3);        // rounds to min normal
    return s | keep;
  }
}

// ---------------- Kernel A: gather k,v + attention softmax w ----------------
__global__ __launch_bounds__(256) void k_gather_attn(
    const int* __restrict__ q, const int* __restrict__ r,
    const float* __restrict__ k_emb, const float* __restrict__ x_emb,
    const float* __restrict__ Mk,
    float* __restrict__ X2, float* __restrict__ vbuf, float* __restrict__ wbuf)
{
  __shared__ float ks[4][DS];
  const int tid = threadIdx.x;
  const int wv = tid >> 6, ln = tid & 63;
  const int row = blockIdx.x * 4 + wv;
  const int b = row / SEQ, s = row % SEQ;
  const int qi = q[b*SEQ + s];
  const int ri = r[b*SEQ + s];
  const float4* kr = (const float4*)(k_emb + (size_t)qi * DS);
  const float4* vr = (const float4*)(x_emb + ((size_t)qi + (size_t)NSK * ri) * DS);
  float4 kv = kr[ln];
  float4 vv = vr[ln];
  ((float4*)(X2 + (size_t)row*512 + DS))[ln] = kv;
  ((float4*)(vbuf + (size_t)row*DS))[ln] = vv;
  *((float4*)&ks[wv][ln*4]) = kv;
  __syncthreads();
  const float4* mkr = (const float4*)(Mk + (size_t)ln * DS);
  float a0=0.f,a1=0.f,a2=0.f,a3=0.f;
  #pragma unroll 8
  for (int d4=0; d4<DS/4; d4++){
    float4 m4 = mkr[d4];
    float4 k4 = *((const float4*)&ks[wv][d4*4]);
    a0 += m4.x*k4.x; a1 += m4.y*k4.y; a2 += m4.z*k4.z; a3 += m4.w*k4.w;
  }
  float lg = (a0+a1)+(a2+a3);
  float mx = lg;
  #pragma unroll
  for (int off=32; off; off>>=1) mx = fmaxf(mx, __shfl_xor(mx, off));
  float ex = expf(lg - mx);
  float sm = ex;
  #pragma unroll
  for (int off=32; off; off>>=1) sm += __shfl_xor(sm, off);
  wbuf[(size_t)row*SM + ln] = ex / sm;
}

// ---------------- bf16 MFMA GEMM: C = act(A @ W^T + bias [+bias2]) ----------
// ABF: A is bf16 (else f32). OUT: 0 f32 linear, 1 bf16 linear, 2 bf16 gate-
// interleaved ([m][ (n&255)*4 + (n>>8) ], for the LSTM's gin layout).
template<int ACT, int ABF, int OUT>
__global__ __launch_bounds__(256) void k_gemm2(
    const void* __restrict__ A0, int lda0, int K0,
    const void* __restrict__ A1, int lda1, int K1,
    const float* __restrict__ W, const float* __restrict__ bias,
    const float* __restrict__ bias2,
    void* __restrict__ C, int N)
{
  const int K = K0 + K1;
  __shared__ __align__(16) char As[64*80];
  __shared__ __align__(16) char Bs[64*80];
  const int tid = threadIdx.x;
  const int l = tid & 63, w = tid >> 6;
  const int m0 = blockIdx.x * 64, n0 = blockIdx.y * 64;
  const int mh = w >> 1, nh = w & 1;
  const int srow = tid >> 2, sseg = tid & 3;

  f32x4 acc[2][2];
  #pragma unroll
  for (int i=0;i<2;i++)
    #pragma unroll
    for (int j=0;j<2;j++) acc[i][j] = (f32x4){0.f,0.f,0.f,0.f};

  for (int k0=0; k0<K; k0+=32){
    const int kk = k0 + sseg*8;
    bf16x8 av;
    if (ABF){
      const ushort* ap = (kk < K0) ? (const ushort*)A0 + (size_t)(m0+srow)*lda0 + kk
                                   : (const ushort*)A1 + (size_t)(m0+srow)*lda1 + (kk-K0);
      av = *(const bf16x8*)ap;
    } else {
      const float* ap = (kk < K0) ? (const float*)A0 + (size_t)(m0+srow)*lda0 + kk
                                  : (const float*)A1 + (size_t)(m0+srow)*lda1 + (kk-K0);
      float4 a1 = *(const float4*)ap;
      float4 a2 = *(const float4*)(ap+4);
      av[0]=f2bf(a1.x); av[1]=f2bf(a1.y); av[2]=f2bf(a1.z); av[3]=f2bf(a1.w);
      av[4]=f2bf(a2.x); av[5]=f2bf(a2.y); av[6]=f2bf(a2.z); av[7]=f2bf(a2.w);
    }
    *(bf16x8*)(As + srow*80 + ((sseg ^ (srow&3))*16)) = av;
    const float* wp = W + (size_t)(n0+srow)*K + kk;
    float4 b1 = *(const float4*)wp;
    float4 b2 = *(const float4*)(wp+4);
    bf16x8 bv;
    bv[0]=f2bf(b1.x); bv[1]=f2bf(b1.y); bv[2]=f2bf(b1.z); bv[3]=f2bf(b1.w);
    bv[4]=f2bf(b2.x); bv[5]=f2bf(b2.y); bv[6]=f2bf(b2.z); bv[7]=f2bf(b2.w);
    *(bf16x8*)(Bs + srow*80 + ((sseg ^ (srow&3))*16)) = bv;
    __syncthreads();
    bf16x8 af[2], bf[2];
    #pragma unroll
    for (int mi=0; mi<2; mi++){
      const int row = mh*32 + mi*16 + (l&15);
      af[mi] = *(const bf16x8*)(As + row*80 + (((l>>4) ^ (row&3))*16));
    }
    #pragma unroll
    for (int ni=0; ni<2; ni++){
      const int row = nh*32 + ni*16 + (l&15);
      bf[ni] = *(const bf16x8*)(Bs + row*80 + (((l>>4) ^ (row&3))*16));
    }
    #pragma unroll
    for (int mi=0; mi<2; mi++)
      #pragma unroll
      for (int ni=0; ni<2; ni++)
        acc[mi][ni] = __builtin_amdgcn_mfma_f32_16x16x32_bf16(af[mi], bf[ni], acc[mi][ni], 0,0,0);
    __syncthreads();
  }
  #pragma unroll
  for (int mi=0; mi<2; mi++){
    #pragma unroll
    for (int ni=0; ni<2; ni++){
      const int n = n0 + nh*32 + ni*16 + (l&15);
      float bsum = bias[n] + (bias2 ? bias2[n] : 0.f);
      #pragma unroll
      for (int j=0;j<4;j++){
        const int m = m0 + mh*32 + mi*16 + (l>>4)*4 + j;
        float v = acc[mi][ni][j] + bsum;
        if (ACT==1) v = sigf(v);
        else if (ACT==2) v = tanhf(v);
        if (OUT==0)      ((float*)C)[(size_t)m*N + n] = v;
        else if (OUT==1) ((ushort*)C)[(size_t)m*N + n] = (ushort)f2bf(v);
        else             ((ushort*)C)[(size_t)m*N + ((n&255)*4 + (n>>8))] = (ushort)f2bf(v);
      }
    }
  }
}

// ---------------- fused erase/add GEMM (shared A = webuf bf16) --------------
__global__ __launch_bounds__(256) void k_gemm_ea(
    const ushort* __restrict__ A, const float* __restrict__ W_e,
    const float* __restrict__ b_e, const float* __restrict__ W_add,
    const float* __restrict__ b_add,
    float* __restrict__ ebuf, float* __restrict__ abuf)
{
  __shared__ __align__(16) char As[64*80];
  __shared__ __align__(16) char Bse[64*80];
  __shared__ __align__(16) char Bsa[64*80];
  const int tid = threadIdx.x;
  const int l = tid & 63, w = tid >> 6;
  const int m0 = blockIdx.x * 64, n0 = blockIdx.y * 64;
  const int mh = w >> 1, nh = w & 1;
  const int srow = tid >> 2, sseg = tid & 3;

  f32x4 acce[2][2], acca[2][2];
  #pragma unroll
  for (int i=0;i<2;i++)
    #pragma unroll
    for (int j=0;j<2;j++){ acce[i][j]=(f32x4){0.f,0.f,0.f,0.f}; acca[i][j]=(f32x4){0.f,0.f,0.f,0.f}; }

  for (int k0=0; k0<DS; k0+=32){
    const int kk = k0 + sseg*8;
    bf16x8 av = *(const bf16x8*)(A + (size_t)(m0+srow)*DS + kk);
    *(bf16x8*)(As + srow*80 + ((sseg ^ (srow&3))*16)) = av;
    {
      const float* wp = W_e + (size_t)(n0+srow)*DS + kk;
      float4 b1 = *(const float4*)wp; float4 b2 = *(const float4*)(wp+4);
      bf16x8 bv;
      bv[0]=f2bf(b1.x); bv[1]=f2bf(b1.y); bv[2]=f2bf(b1.z); bv[3]=f2bf(b1.w);
      bv[4]=f2bf(b2.x); bv[5]=f2bf(b2.y); bv[6]=f2bf(b2.z); bv[7]=f2bf(b2.w);
      *(bf16x8*)(Bse + srow*80 + ((sseg ^ (srow&3))*16)) = bv;
    }
    {
      const float* wp = W_add + (size_t)(n0+srow)*DS + kk;
      float4 b1 = *(const float4*)wp; float4 b2 = *(const float4*)(wp+4);
      bf16x8 bv;
      bv[0]=f2bf(b1.x); bv[1]=f2bf(b1.y); bv[2]=f2bf(b1.z); bv[3]=f2bf(b1.w);
      bv[4]=f2bf(b2.x); bv[5]=f2bf(b2.y); bv[6]=f2bf(b2.z); bv[7]=f2bf(b2.w);
      *(bf16x8*)(Bsa + srow*80 + ((sseg ^ (srow&3))*16)) = bv;
    }
    __syncthreads();
    bf16x8 af[2], bfe[2], bfa[2];
    #pragma unroll
    for (int mi=0; mi<2; mi++){
      const int row = mh*32 + mi*16 + (l&15);
      af[mi] = *(const bf16x8*)(As + row*80 + (((l>>4) ^ (row&3))*16));
    }
    #pragma unroll
    for (int ni=0; ni<2; ni++){
      const int row = nh*32 + ni*16 + (l&15);
      bfe[ni] = *(const bf16x8*)(Bse + row*80 + (((l>>4) ^ (row&3))*16));
      bfa[ni] = *(const bf16x8*)(Bsa + row*80 + (((l>>4) ^ (row&3))*16));
    }
    #pragma unroll
    for (int mi=0; mi<2; mi++)
      #pragma unroll
      for (int ni=0; ni<2; ni++){
        acce[mi][ni] = __builtin_amdgcn_mfma_f32_16x16x32_bf16(af[mi], bfe[ni], acce[mi][ni], 0,0,0);
        acca[mi][ni] = __builtin_amdgcn_mfma_f32_16x16x32_bf16(af[mi], bfa[ni], acca[mi][ni], 0,0,0);
      }
    __syncthreads();
  }
  #pragma unroll
  for (int mi=0; mi<2; mi++){
    #pragma unroll
    for (int ni=0; ni<2; ni++){
      const int n = n0 + nh*32 + ni*16 + (l&15);
      const float be = b_e[n], ba = b_add[n];
      #pragma unroll
      for (int j=0;j<4;j++){
        const int m = m0 + mh*32 + mi*16 + (l>>4)*4 + j;
        ebuf[(size_t)m*DS + n] = sigf(acce[mi][ni][j] + be);
        abuf[(size_t)m*DS + n] = tanhf(acca[mi][ni][j] + ba);
      }
    }
  }
}

// ---------------- Memory scan (sequential over t) ---------------------------
__global__ __launch_bounds__(256) void k_scan(
    const float* __restrict__ wbuf, const float* __restrict__ ebuf,
    const float* __restrict__ abuf, const float* __restrict__ Mv0,
    float* __restrict__ X2)
{
  const int b = blockIdx.x;
  const int d = threadIdx.x;
  __shared__ float ws[SM];
  float mem[SM];
  #pragma unroll
  for (int m=0;m<SM;m++) mem[m] = Mv0[m*DS + d];
  for (int t=0;t<SEQ;t++){
    const size_t row = (size_t)b*SEQ + t;
    if (d < SM) ws[d] = wbuf[row*SM + d];
    const float e = ebuf[row*DS + d];
    const float a = abuf[row*DS + d];
    __syncthreads();
    float r0=0.f,r1=0.f,r2=0.f,r3=0.f;
    #pragma unroll
    for (int m=0;m<SM;m+=4){
      float w0=ws[m], w1=ws[m+1], w2=ws[m+2], w3=ws[m+3];
      r0 += w0*mem[m];   mem[m]   += w0*fmaf(-e, mem[m],   a);
      r1 += w1*mem[m+1]; mem[m+1] += w1*fmaf(-e, mem[m+1], a);
      r2 += w2*mem[m+2]; mem[m+2] += w2*fmaf(-e, mem[m+2], a);
      r3 += w3*mem[m+3]; mem[m+3] += w3*fmaf(-e, mem[m+3], a);
    }
    X2[row*512 + d] = (r0+r1)+(r2+r3);
    __syncthreads();
  }
}

// ---------------- Zero-communication LSTM, FP8 weights -----------------------
// 4 blocks x 512 threads; block g owns batches [16g,+16). Full W_hh as e4m3
// (x64 scale): per wave 64 frags of 8B -> 26 in VGPR (52 regs) + 38 in LDS.
// h kept as e4m3 (x16 scale) in a 4KB swizzled LDS tile. Total live regs ~120
// (<= the observed 128 allocator cap -> no spill). acc rescaled by 2^-10.
__global__ __launch_bounds__(512) void k_lstm_nc(
    const ushort* __restrict__ gin2, const float* __restrict__ W_hh,
    const float* __restrict__ hx, const float* __restrict__ cx,
    short* __restrict__ hhist)
{
  extern __shared__ char L[];
  char* hsm  = L;                 // 4KB: 16 rows x 256B fp8, byte-XOR swizzled
  char* wlds = L + 4096;          // 38 slots/wave x 512B (lane-linear, conflict-free)

  const int g = blockIdx.x;
  const int tid = threadIdx.x;
  const int l = tid & 63, w = tid >> 6;

  // ---- setup: W_hh -> e4m3 frags (x64). f = (half*4+gt)*8 + kt.
  // lane l holds W[G][k]*64, G = gt*256 + w*32 + half*16 + (l&15),
  // k = kt*32 + (l>>4)*8 + jj  (byte jj of the 8B frag)
  u64 wv[FP8_VG];
  #pragma unroll
  for (int nt=0; nt<8; nt++){
    const int half = nt >> 2, gt = nt & 3;
    const int G = gt*256 + w*32 + half*16 + (l & 15);
    const float* wrow = W_hh + (size_t)G*256;
    #pragma unroll
    for (int kt=0; kt<8; kt++){
      const int f = nt*8 + kt;
      const int k0 = kt*32 + (l>>4)*8;
      float4 wa = *(const float4*)(wrow + k0);
      float4 wb = *(const float4*)(wrow + k0 + 4);
      u64 v =  (u64)f2e4m3(wa.x*64.f)
            | ((u64)f2e4m3(wa.y*64.f) << 8)
            | ((u64)f2e4m3(wa.z*64.f) << 16)
            | ((u64)f2e4m3(wa.w*64.f) << 24)
            | ((u64)f2e4m3(wb.x*64.f) << 32)
            | ((u64)f2e4m3(wb.y*64.f) << 40)
            | ((u64)f2e4m3(wb.z*64.f) << 48)
            | ((u64)f2e4m3(wb.w*64.f) << 56);
      if (f < FP8_VG) wv[f] = v;
      else *(u64*)(wlds + ((w*FP8_LDS + (f - FP8_VG)) << 9) + l*8) = v;
    }
  }

  // ---- c init: lane owns (b,d) for half 0..1, j 0..3 ----
  float c_[8];
  #pragma unroll
  for (int half=0; half<2; half++){
    const float c0 = cx[w*32 + half*16 + (l & 15)];
    #pragma unroll
    for (int j=0;j<4;j++) c_[half*4+j] = c0;
  }

  // ---- stage hx (x16, e4m3) into hsm: all 16 rows identical ----
  if (tid < 256){
    const unsigned char hv = (unsigned char)f2e4m3(hx[tid]*16.f);
    #pragma unroll
    for (int rr=0; rr<16; rr++)
      hsm[rr*256 + (tid ^ ((rr&7)<<3))] = (char)hv;
  }
  __syncthreads();

  // running pointers
  const int b0 = g*16 + (l>>4)*4;
  const int d0 = w*32 + (l & 15);
  const char* gp = (const char*)gin2 + ((size_t)(b0*SEQ)*1024 + d0*4)*2;
  char* hp = (char*)hhist + ((size_t)(b0*SEQ)*256 + d0)*2;

  for (int t=0; t<SEQ; t++){
    unsigned char h8[8];
    #pragma unroll
    for (int half=0; half<2; half++){
      // gin loads for this half (latency hidden under MFMA)
      u64 gld[4];
      #pragma unroll
      for (int j=0;j<4;j++)
        gld[j] = *(const u64*)(gp + (size_t)j*(SEQ*2048) + half*128);
      // MFMA over K=256 for the 4 gates of this half
      f32x4 acc[4];
      #pragma unroll
      for (int gt=0; gt<4; gt++) acc[gt] = (f32x4){0.f,0.f,0.f,0.f};
      const int r0 = l & 15;
      #pragma unroll
      for (int kt=0; kt<8; kt++){
        const int c0 = kt*32 + (l>>4)*8;
        long a = *(const long*)(hsm + r0*256 + (c0 ^ ((r0&7)<<3)));
        #pragma unroll
        for (int gt=0; gt<4; gt++){
          const int f = (half*4 + gt)*8 + kt;
          long b;
          if (f < FP8_VG) b = (long)wv[f];
          else b = *(const long*)(wlds + ((w*FP8_LDS + (f - FP8_VG)) << 9) + l*8);
          acc[gt] = __builtin_amdgcn_mfma_f32_16x16x32_fp8_fp8(a, b, acc[gt], 0,0,0);
        }
      }
      // gates (acc carries x1024 scale)
      #pragma unroll
      for (int j=0;j<4;j++){
        const u64 gv = gld[j];
        float iv = acc[0][j]*9.765625e-4f + bf2f((unsigned short)(gv       & 0xffffu));
        float fv = acc[1][j]*9.765625e-4f + bf2f((unsigned short)((gv>>16) & 0xffffu));
        float gg = acc[2][j]*9.765625e-4f + bf2f((unsigned short)((gv>>32) & 0xffffu));
        float ov = acc[3][j]*9.765625e-4f + bf2f((unsigned short)((gv>>48) & 0xffffu));
        float cc = fast_sig(fv)*c_[half*4+j] + fast_sig(iv)*fast_tanh(gg);
        c_[half*4+j] = cc;
        float h = fast_sig(ov)*fast_tanh(cc);
        *(short*)(hp + (size_t)j*(SEQ*512) + half*32) = f2bf(h);
        h8[half*4+j] = (unsigned char)f2e4m3(h*16.f);
      }
    }
    gp += 2048;
    hp += 512;
    __syncthreads();   // all reads of h(t-1) complete
    #pragma unroll
    for (int half=0; half<2; half++)
      #pragma unroll
      for (int j=0;j<4;j++){
        const int rr = (l>>4)*4 + j;
        const int dd = w*32 + half*16 + (l & 15);
        hsm[rr*256 + (dd ^ ((rr&7)<<3))] = (char)h8[half*4+j];
      }
    __syncthreads();   // h(t) staged
  }
}

// ---------------- p output: sigmoid(h . W_p + b_p) --------------------------
__global__ __launch_bounds__(256) void k_pout(
    const short* __restrict__ hhist, const float* __restrict__ W_p,
    const float* __restrict__ b_p, float* __restrict__ out)
{
  const int tid = threadIdx.x;
  const int row = blockIdx.x*4 + (tid>>6);
  const int ln = tid & 63;
  ushort4 hv = ((const ushort4*)(hhist + (size_t)row*256))[ln];
  float4 wp = ((const float4*)W_p)[ln];
  float s = bf2f(hv.x)*wp.x + bf2f(hv.y)*wp.y + bf2f(hv.z)*wp.z + bf2f(hv.w)*wp.w;
  #pragma unroll
  for (int off=32; off; off>>=1) s += __shfl_xor(s, off);
  if (ln == 0) out[row] = sigf(s + b_p[0]);
}

extern "C" void kernel_launch(void* const* d_in, const int* in_sizes, int n_in,
                              void* d_out, int out_size, void* d_ws, size_t ws_size,
                              hipStream_t stream)
{
  const int*   q     = (const int*)d_in[0];
  const int*   r     = (const int*)d_in[1];
  const float* k_emb = (const float*)d_in[2];
  const float* x_emb = (const float*)d_in[3];
  const float* Mk    = (const float*)d_in[4];
  const float* Mv0   = (const float*)d_in[5];
  const float* W_a   = (const float*)d_in[6];
  const float* b_a   = (const float*)d_in[7];
  const float* W_e   = (const float*)d_in[8];
  const float* b_e   = (const float*)d_in[9];
  const float* W_add = (const float*)d_in[10];
  const float* b_add = (const float*)d_in[11];
  const float* W_f   = (const float*)d_in[12];
  const float* b_f   = (const float*)d_in[13];
  const float* hx    = (const float*)d_in[14];
  const float* cx    = (const float*)d_in[15];
  const float* W_ih  = (const float*)d_in[16];
  const float* b_ih  = (const float*)d_in[17];
  const float* W_hh  = (const float*)d_in[18];
  const float* b_hh  = (const float*)d_in[19];
  const float* W_p   = (const float*)d_in[20];
  const float* b_p   = (const float*)d_in[21];
  float* out = (float*)d_out;

  // byte-offset workspace layout
  char* base = (char*)d_ws;
  float*  vbuf  = (float*)(base);                          // 13.1MB
  ushort* webuf = (ushort*)(base + 13107200);              // 6.55MB
  float*  ebuf  = (float*)(base + 19660800);               // 13.1MB
  float*  abuf  = (float*)(base + 32768000);               // 13.1MB
  float*  X2    = (float*)(base + 45875200);               // 26.2MB [reads|k]
  float*  wbuf  = (float*)(base + 72089600);               // 3.3MB
  ushort* fbuf  = (ushort*)(base + 75366400);              // 6.55MB
  ushort* gin2  = (ushort*)(base);                         // 26.2MB overlay (vbuf..ebuf dead)
  short*  hhist = (short*)fbuf;                            // overlay (fbuf dead post-gin)

  k_gather_attn<<<NROWS/4, 256, 0, stream>>>(q, r, k_emb, x_emb, Mk, X2, vbuf, wbuf);
  // we = [k|v] @ W_a^T + b_a  -> bf16
  k_gemm2<0,0,1><<<dim3(NROWS/64, 4), 256, 0, stream>>>(X2+DS, 512, DS, vbuf, DS, DS, W_a, b_a, nullptr, webuf, DS);
  // erase/add fused (A = webuf bf16)
  k_gemm_ea<<<dim3(NROWS/64, 4), 256, 0, stream>>>(webuf, W_e, b_e, W_add, b_add, ebuf, abuf);
  // memory scan -> reads into X2[:,0:256]
  k_scan<<<BS, DS, 0, stream>>>(wbuf, ebuf, abuf, Mv0, X2);
  // f = tanh([reads|k] @ W_f^T + b_f) -> bf16
  k_gemm2<2,0,1><<<dim3(NROWS/64, 4), 256, 0, stream>>>(X2, 512, DS, X2+DS, 512, DS, W_f, b_f, nullptr, fbuf, DS);
  // gin = f @ W_ih^T + (b_ih + b_hh) -> bf16 gate-interleaved
  k_gemm2<0,1,2><<<dim3(NROWS/64, 16), 256, 0, stream>>>(fbuf, DS, DS, fbuf, DS, 0, W_ih, b_ih, b_hh, gin2, 1024);
  // zero-comm FP8 LSTM
  hipFuncSetAttribute((const void*)k_lstm_nc,
                      hipFuncAttributeMaxDynamicSharedMemorySize, LSTM_LDS);
  k_lstm_nc<<<4, 512, LSTM_LDS, stream>>>(gin2, W_hh, hx, cx, hhist);
  // p = sigmoid(h . W_p + b_p)
  k_pout<<<NROWS/4, 256, 0, stream>>>(hhist, W_p, b_p, out);
}

// Round 9
// 1039.042 us; speedup vs baseline: 1.9910x; 1.9910x over previous
//
#include <hip/hip_runtime.h>
#include <hip/hip_bf16.h>

#define BS 64
#define SEQ 200
#define NSK 4096
#define DS 256
#define SM 64
#define NROWS (BS*SEQ)
#define LBLK 8   // 4 independent pairs x 2 blocks

typedef __attribute__((ext_vector_type(8))) short bf16x8;
typedef __attribute__((ext_vector_type(4))) float f32x4;
typedef unsigned long long u64;

__device__ __forceinline__ float sigf(float x){ return 1.0f/(1.0f+expf(-x)); }
__device__ __forceinline__ float fast_sig(float x){ return 1.0f/(1.0f+__expf(-x)); }
__device__ __forceinline__ float fast_tanh(float x){
  float t = __expf(-2.0f*fabsf(x));
  float r = (1.0f - t)/(1.0f + t);
  return copysignf(r, x);
}
__device__ __forceinline__ short f2bf(float x){
  unsigned int u = __float_as_uint(x);
  unsigned int r = (u + 0x7fffu + ((u >> 16) & 1u)) >> 16;
  return (short)r;
}
__device__ __forceinline__ float bf2f(unsigned short s){
  return __uint_as_float(((unsigned int)s) << 16);
}

// ---------------- Kernel A: gather k,v + attention softmax w ----------------
__global__ __launch_bounds__(256) void k_gather_attn(
    const int* __restrict__ q, const int* __restrict__ r,
    const float* __restrict__ k_emb, const float* __restrict__ x_emb,
    const float* __restrict__ Mk,
    float* __restrict__ X2, float* __restrict__ vbuf, float* __restrict__ wbuf)
{
  __shared__ float ks[4][DS];
  const int tid = threadIdx.x;
  const int wv = tid >> 6, ln = tid & 63;
  const int row = blockIdx.x * 4 + wv;
  const int b = row / SEQ, s = row % SEQ;
  const int qi = q[b*SEQ + s];
  const int ri = r[b*SEQ + s];
  const float4* kr = (const float4*)(k_emb + (size_t)qi * DS);
  const float4* vr = (const float4*)(x_emb + ((size_t)qi + (size_t)NSK * ri) * DS);
  float4 kv = kr[ln];
  float4 vv = vr[ln];
  ((float4*)(X2 + (size_t)row*512 + DS))[ln] = kv;
  ((float4*)(vbuf + (size_t)row*DS))[ln] = vv;
  *((float4*)&ks[wv][ln*4]) = kv;
  __syncthreads();
  const float4* mkr = (const float4*)(Mk + (size_t)ln * DS);
  float a0=0.f,a1=0.f,a2=0.f,a3=0.f;
  #pragma unroll 8
  for (int d4=0; d4<DS/4; d4++){
    float4 m4 = mkr[d4];
    float4 k4 = *((const float4*)&ks[wv][d4*4]);
    a0 += m4.x*k4.x; a1 += m4.y*k4.y; a2 += m4.z*k4.z; a3 += m4.w*k4.w;
  }
  float lg = (a0+a1)+(a2+a3);
  float mx = lg;
  #pragma unroll
  for (int off=32; off; off>>=1) mx = fmaxf(mx, __shfl_xor(mx, off));
  float ex = expf(lg - mx);
  float sm = ex;
  #pragma unroll
  for (int off=32; off; off>>=1) sm += __shfl_xor(sm, off);
  wbuf[(size_t)row*SM + ln] = ex / sm;
}

// ---------------- bf16 MFMA GEMM: C = act(A @ W^T + bias [+bias2]) ----------
// ABF: A is bf16 (else f32). OUT: 0 f32 linear, 1 bf16 linear, 2 bf16 gate-
// interleaved ([m][ (n&255)*4 + (n>>8) ], for the LSTM's gin layout).
template<int ACT, int ABF, int OUT>
__global__ __launch_bounds__(256) void k_gemm2(
    const void* __restrict__ A0, int lda0, int K0,
    const void* __restrict__ A1, int lda1, int K1,
    const float* __restrict__ W, const float* __restrict__ bias,
    const float* __restrict__ bias2,
    void* __restrict__ C, int N)
{
  const int K = K0 + K1;
  __shared__ __align__(16) char As[64*80];
  __shared__ __align__(16) char Bs[64*80];
  const int tid = threadIdx.x;
  const int l = tid & 63, w = tid >> 6;
  const int m0 = blockIdx.x * 64, n0 = blockIdx.y * 64;
  const int mh = w >> 1, nh = w & 1;
  const int srow = tid >> 2, sseg = tid & 3;

  f32x4 acc[2][2];
  #pragma unroll
  for (int i=0;i<2;i++)
    #pragma unroll
    for (int j=0;j<2;j++) acc[i][j] = (f32x4){0.f,0.f,0.f,0.f};

  for (int k0=0; k0<K; k0+=32){
    const int kk = k0 + sseg*8;
    bf16x8 av;
    if (ABF){
      const ushort* ap = (kk < K0) ? (const ushort*)A0 + (size_t)(m0+srow)*lda0 + kk
                                   : (const ushort*)A1 + (size_t)(m0+srow)*lda1 + (kk-K0);
      av = *(const bf16x8*)ap;
    } else {
      const float* ap = (kk < K0) ? (const float*)A0 + (size_t)(m0+srow)*lda0 + kk
                                  : (const float*)A1 + (size_t)(m0+srow)*lda1 + (kk-K0);
      float4 a1 = *(const float4*)ap;
      float4 a2 = *(const float4*)(ap+4);
      av[0]=f2bf(a1.x); av[1]=f2bf(a1.y); av[2]=f2bf(a1.z); av[3]=f2bf(a1.w);
      av[4]=f2bf(a2.x); av[5]=f2bf(a2.y); av[6]=f2bf(a2.z); av[7]=f2bf(a2.w);
    }
    *(bf16x8*)(As + srow*80 + ((sseg ^ (srow&3))*16)) = av;
    const float* wp = W + (size_t)(n0+srow)*K + kk;
    float4 b1 = *(const float4*)wp;
    float4 b2 = *(const float4*)(wp+4);
    bf16x8 bv;
    bv[0]=f2bf(b1.x); bv[1]=f2bf(b1.y); bv[2]=f2bf(b1.z); bv[3]=f2bf(b1.w);
    bv[4]=f2bf(b2.x); bv[5]=f2bf(b2.y); bv[6]=f2bf(b2.z); bv[7]=f2bf(b2.w);
    *(bf16x8*)(Bs + srow*80 + ((sseg ^ (srow&3))*16)) = bv;
    __syncthreads();
    bf16x8 af[2], bf[2];
    #pragma unroll
    for (int mi=0; mi<2; mi++){
      const int row = mh*32 + mi*16 + (l&15);
      af[mi] = *(const bf16x8*)(As + row*80 + (((l>>4) ^ (row&3))*16));
    }
    #pragma unroll
    for (int ni=0; ni<2; ni++){
      const int row = nh*32 + ni*16 + (l&15);
      bf[ni] = *(const bf16x8*)(Bs + row*80 + (((l>>4) ^ (row&3))*16));
    }
    #pragma unroll
    for (int mi=0; mi<2; mi++)
      #pragma unroll
      for (int ni=0; ni<2; ni++)
        acc[mi][ni] = __builtin_amdgcn_mfma_f32_16x16x32_bf16(af[mi], bf[ni], acc[mi][ni], 0,0,0);
    __syncthreads();
  }
  #pragma unroll
  for (int mi=0; mi<2; mi++){
    #pragma unroll
    for (int ni=0; ni<2; ni++){
      const int n = n0 + nh*32 + ni*16 + (l&15);
      float bsum = bias[n] + (bias2 ? bias2[n] : 0.f);
      #pragma unroll
      for (int j=0;j<4;j++){
        const int m = m0 + mh*32 + mi*16 + (l>>4)*4 + j;
        float v = acc[mi][ni][j] + bsum;
        if (ACT==1) v = sigf(v);
        else if (ACT==2) v = tanhf(v);
        if (OUT==0)      ((float*)C)[(size_t)m*N + n] = v;
        else if (OUT==1) ((ushort*)C)[(size_t)m*N + n] = (ushort)f2bf(v);
        else             ((ushort*)C)[(size_t)m*N + ((n&255)*4 + (n>>8))] = (ushort)f2bf(v);
      }
    }
  }
}

// ---------------- fused erase/add GEMM (shared A = webuf bf16) --------------
__global__ __launch_bounds__(256) void k_gemm_ea(
    const ushort* __restrict__ A, const float* __restrict__ W_e,
    const float* __restrict__ b_e, const float* __restrict__ W_add,
    const float* __restrict__ b_add,
    float* __restrict__ ebuf, float* __restrict__ abuf)
{
  __shared__ __align__(16) char As[64*80];
  __shared__ __align__(16) char Bse[64*80];
  __shared__ __align__(16) char Bsa[64*80];
  const int tid = threadIdx.x;
  const int l = tid & 63, w = tid >> 6;
  const int m0 = blockIdx.x * 64, n0 = blockIdx.y * 64;
  const int mh = w >> 1, nh = w & 1;
  const int srow = tid >> 2, sseg = tid & 3;

  f32x4 acce[2][2], acca[2][2];
  #pragma unroll
  for (int i=0;i<2;i++)
    #pragma unroll
    for (int j=0;j<2;j++){ acce[i][j]=(f32x4){0.f,0.f,0.f,0.f}; acca[i][j]=(f32x4){0.f,0.f,0.f,0.f}; }

  for (int k0=0; k0<DS; k0+=32){
    const int kk = k0 + sseg*8;
    bf16x8 av = *(const bf16x8*)(A + (size_t)(m0+srow)*DS + kk);
    *(bf16x8*)(As + srow*80 + ((sseg ^ (srow&3))*16)) = av;
    {
      const float* wp = W_e + (size_t)(n0+srow)*DS + kk;
      float4 b1 = *(const float4*)wp; float4 b2 = *(const float4*)(wp+4);
      bf16x8 bv;
      bv[0]=f2bf(b1.x); bv[1]=f2bf(b1.y); bv[2]=f2bf(b1.z); bv[3]=f2bf(b1.w);
      bv[4]=f2bf(b2.x); bv[5]=f2bf(b2.y); bv[6]=f2bf(b2.z); bv[7]=f2bf(b2.w);
      *(bf16x8*)(Bse + srow*80 + ((sseg ^ (srow&3))*16)) = bv;
    }
    {
      const float* wp = W_add + (size_t)(n0+srow)*DS + kk;
      float4 b1 = *(const float4*)wp; float4 b2 = *(const float4*)(wp+4);
      bf16x8 bv;
      bv[0]=f2bf(b1.x); bv[1]=f2bf(b1.y); bv[2]=f2bf(b1.z); bv[3]=f2bf(b1.w);
      bv[4]=f2bf(b2.x); bv[5]=f2bf(b2.y); bv[6]=f2bf(b2.z); bv[7]=f2bf(b2.w);
      *(bf16x8*)(Bsa + srow*80 + ((sseg ^ (srow&3))*16)) = bv;
    }
    __syncthreads();
    bf16x8 af[2], bfe[2], bfa[2];
    #pragma unroll
    for (int mi=0; mi<2; mi++){
      const int row = mh*32 + mi*16 + (l&15);
      af[mi] = *(const bf16x8*)(As + row*80 + (((l>>4) ^ (row&3))*16));
    }
    #pragma unroll
    for (int ni=0; ni<2; ni++){
      const int row = nh*32 + ni*16 + (l&15);
      bfe[ni] = *(const bf16x8*)(Bse + row*80 + (((l>>4) ^ (row&3))*16));
      bfa[ni] = *(const bf16x8*)(Bsa + row*80 + (((l>>4) ^ (row&3))*16));
    }
    #pragma unroll
    for (int mi=0; mi<2; mi++)
      #pragma unroll
      for (int ni=0; ni<2; ni++){
        acce[mi][ni] = __builtin_amdgcn_mfma_f32_16x16x32_bf16(af[mi], bfe[ni], acce[mi][ni], 0,0,0);
        acca[mi][ni] = __builtin_amdgcn_mfma_f32_16x16x32_bf16(af[mi], bfa[ni], acca[mi][ni], 0,0,0);
      }
    __syncthreads();
  }
  #pragma unroll
  for (int mi=0; mi<2; mi++){
    #pragma unroll
    for (int ni=0; ni<2; ni++){
      const int n = n0 + nh*32 + ni*16 + (l&15);
      const float be = b_e[n], ba = b_add[n];
      #pragma unroll
      for (int j=0;j<4;j++){
        const int m = m0 + mh*32 + mi*16 + (l>>4)*4 + j;
        ebuf[(size_t)m*DS + n] = sigf(acce[mi][ni][j] + be);
        abuf[(size_t)m*DS + n] = tanhf(acca[mi][ni][j] + ba);
      }
    }
  }
}

// ---------------- Memory scan (sequential over t) ---------------------------
__global__ __launch_bounds__(256) void k_scan(
    const float* __restrict__ wbuf, const float* __restrict__ ebuf,
    const float* __restrict__ abuf, const float* __restrict__ Mv0,
    float* __restrict__ X2)
{
  const int b = blockIdx.x;
  const int d = threadIdx.x;
  __shared__ float ws[SM];
  float mem[SM];
  #pragma unroll
  for (int m=0;m<SM;m++) mem[m] = Mv0[m*DS + d];
  for (int t=0;t<SEQ;t++){
    const size_t row = (size_t)b*SEQ + t;
    if (d < SM) ws[d] = wbuf[row*SM + d];
    const float e = ebuf[row*DS + d];
    const float a = abuf[row*DS + d];
    __syncthreads();
    float r0=0.f,r1=0.f,r2=0.f,r3=0.f;
    #pragma unroll
    for (int m=0;m<SM;m+=4){
      float w0=ws[m], w1=ws[m+1], w2=ws[m+2], w3=ws[m+3];
      r0 += w0*mem[m];   mem[m]   += w0*fmaf(-e, mem[m],   a);
      r1 += w1*mem[m+1]; mem[m+1] += w1*fmaf(-e, mem[m+1], a);
      r2 += w2*mem[m+2]; mem[m+2] += w2*fmaf(-e, mem[m+2], a);
      r3 += w3*mem[m+3]; mem[m+3] += w3*fmaf(-e, mem[m+3], a);
    }
    X2[row*512 + d] = (r0+r1)+(r2+r3);
    __syncthreads();
  }
}

// ---------------- Pairwise cooperative MFMA LSTM (tagged-slot exchange) -----
// R5's proven kernel (627us, VGPR=128, clean VALU profile). Only change: gin
// is read as bf16 gate-interleaved u64 (4 loads/step instead of 16 scalars).
// 8 blocks = 4 pairs. Pair p owns batches [16p,+16). Block ro = bb&1 owns dims
// [ro*128,+128), all 4 gates (512 W_hh rows in VGPRs). Cross-block h exchange
// via 64-bit tagged slots: (h_even<<48)|(h_odd<<32)|step_tag.
__global__ __launch_bounds__(512, 2) void k_lstm2(
    const ushort* __restrict__ gin2, const float* __restrict__ W_hh,
    const float* __restrict__ hx, const float* __restrict__ cx,
    short* __restrict__ hhist, unsigned long long* __restrict__ xbuf)
{
  const int bb = blockIdx.x;
  const int p  = bb >> 1;
  const int ro = bb & 1;
  const int tid = threadIdx.x;
  const int l   = tid & 63;
  const int w   = tid >> 6;

  __shared__ short hsm[2][16*256];   // 2 x 8KB, 512B rows, XOR-swizzled

  bf16x8 wfr[4][8];
  {
    const int col  = l & 15;
    const int krow = (l >> 4) * 8;
    #pragma unroll
    for (int gt=0; gt<4; gt++){
      const int G = gt*256 + ro*128 + w*16 + col;
      const float* wrow = W_hh + (size_t)G*256;
      #pragma unroll
      for (int kt=0; kt<8; kt++){
        const int k0 = kt*32 + krow;
        float4 wa = *(const float4*)(wrow + k0);
        float4 wb = *(const float4*)(wrow + k0 + 4);
        bf16x8 f;
        f[0]=f2bf(wa.x); f[1]=f2bf(wa.y); f[2]=f2bf(wa.z); f[3]=f2bf(wa.w);
        f[4]=f2bf(wb.x); f[5]=f2bf(wb.y); f[6]=f2bf(wb.z); f[7]=f2bf(wb.w);
        wfr[gt][kt] = f;
      }
    }
  }

  const int dhalf = w*16 + (l & 15);           // 0..127 within my half
  const int gdim  = ro*128 + dhalf;            // this lane's dim
  float c_[4];
  {
    float c0 = cx[gdim];
    #pragma unroll
    for (int r=0;r<4;r++) c_[r] = c0;
  }

  // stage hx into hsm[0] (full 256 dims, 16 rows)
  if (tid < 256){
    const int row = tid >> 4, seg = tid & 15;
    #pragma unroll
    for (int u=0; u<2; u++){
      const int kb = seg*32 + u*16;
      const int d0 = kb >> 1;
      float4 ha = *(const float4*)(hx + d0);
      float4 hb = *(const float4*)(hx + d0 + 4);
      bf16x8 v;
      v[0]=f2bf(ha.x); v[1]=f2bf(ha.y); v[2]=f2bf(ha.z); v[3]=f2bf(ha.w);
      v[4]=f2bf(hb.x); v[5]=f2bf(hb.y); v[6]=f2bf(hb.z); v[7]=f2bf(hb.w);
      *(bf16x8*)((char*)hsm[0] + row*512 + (kb ^ ((row&7)<<4))) = v;
    }
  }

  // prefetch gin[t=0]: one u64 per batch = all 4 gates for this lane's dim
  u64 gpre[4];
  #pragma unroll
  for (int r=0; r<4; r++){
    const int b = p*16 + (l>>4)*4 + r;
    gpre[r] = *(const u64*)(gin2 + ((size_t)(b*SEQ))*1024 + gdim*4);
  }

  // slot buffers: xbuf[(p*2+ro)*1024 + bat*64 + (dhalf>>1)]
  unsigned long long* myslots = xbuf + (size_t)(p*2 + ro)*1024;
  unsigned long long* pslots  = xbuf + (size_t)(p*2 + (1-ro))*1024;

  for (int t=0; t<SEQ; t++){
    __syncthreads();   // hsm[t&1] fully staged
    const int cur = t & 1;

    f32x4 acc[4];
    #pragma unroll
    for (int gt=0; gt<4; gt++) acc[gt] = (f32x4){0.f,0.f,0.f,0.f};
    const int r0 = l & 15;
    #pragma unroll
    for (int kt=0; kt<8; kt++){
      const int kbyte = kt*64 + (l>>4)*16;
      bf16x8 a = *(const bf16x8*)((const char*)hsm[cur] + r0*512 + (kbyte ^ ((r0&7)<<4)));
      #pragma unroll
      for (int gt=0; gt<4; gt++)
        acc[gt] = __builtin_amdgcn_mfma_f32_16x16x32_bf16(a, wfr[gt][kt], acc[gt], 0,0,0);
    }

    const unsigned int tag = (unsigned int)(t + 1);
    #pragma unroll
    for (int r=0; r<4; r++){
      const int bat = (l>>4)*4 + r;            // block-local batch
      const int b = p*16 + bat;
      const u64 gv = gpre[r];
      float iv = acc[0][r] + bf2f((unsigned short)(gv       & 0xffffu));
      float fv = acc[1][r] + bf2f((unsigned short)((gv>>16) & 0xffffu));
      float gg = acc[2][r] + bf2f((unsigned short)((gv>>32) & 0xffffu));
      float ov = acc[3][r] + bf2f((unsigned short)((gv>>48) & 0xffffu));
      float cc = fast_sig(fv)*c_[r] + fast_sig(iv)*fast_tanh(gg);
      c_[r] = cc;
      float h = fast_sig(ov)*fast_tanh(cc);
      unsigned short hb = (unsigned short)f2bf(h);
      hhist[((size_t)(b*SEQ + t))*256 + gdim] = (short)hb;   // plain; read post-kernel
      *(short*)((char*)hsm[cur^1] + bat*512 + ((gdim*2) ^ ((bat&7)<<4))) = (short)hb;
      // tagged-slot export (even-dim lanes pack self + neighbor)
      unsigned short nb = (unsigned short)__shfl_xor((int)hb, 1);
      if ((l & 1) == 0){
        unsigned long long v = ((unsigned long long)hb << 48)
                             | ((unsigned long long)nb << 32)
                             | (unsigned long long)tag;
        __hip_atomic_store(&myslots[bat*64 + (dhalf>>1)], v,
                           __ATOMIC_RELAXED, __HIP_MEMORY_SCOPE_AGENT);
      }
    }

    if (t == SEQ-1) break;

    // prefetch gin[t+1] while our stores propagate
    #pragma unroll
    for (int r=0; r<4; r++){
      const int b = p*16 + (l>>4)*4 + r;
      gpre[r] = *(const u64*)(gin2 + ((size_t)(b*SEQ + t+1))*1024 + gdim*4);
    }

    // poll partner's 2 slots; write partner half into hsm[cur^1]
    {
      const int s0 = tid*2, s1 = tid*2 + 1;
      unsigned long long v0=0, v1=0;
      bool ok0=false, ok1=false;
      while (true){
        if (!ok0){ v0 = __hip_atomic_load(&pslots[s0], __ATOMIC_RELAXED, __HIP_MEMORY_SCOPE_AGENT);
                   ok0 = ((unsigned int)v0 == tag); }
        if (!ok1){ v1 = __hip_atomic_load(&pslots[s1], __ATOMIC_RELAXED, __HIP_MEMORY_SCOPE_AGENT);
                   ok1 = ((unsigned int)v1 == tag); }
        if (ok0 && ok1) break;
        __builtin_amdgcn_s_sleep(1);
      }
      #pragma unroll
      for (int u=0; u<2; u++){
        unsigned long long v = u ? v1 : v0;
        const int sid = u ? s1 : s0;
        const int bat = sid >> 6;
        const int dp  = sid & 63;
        const int dpart = (1-ro)*128 + dp*2;
        unsigned int wv = (unsigned int)((v >> 48) & 0xffffu)
                        | (((unsigned int)(v >> 32) & 0xffffu) << 16);
        *(unsigned int*)((char*)hsm[cur^1] + bat*512 + ((dpart*2) ^ ((bat&7)<<4))) = wv;
      }
    }
    // next-iteration top __syncthreads covers LDS visibility
  }
}

// ---------------- p output: sigmoid(h . W_p + b_p) --------------------------
__global__ __launch_bounds__(256) void k_pout(
    const short* __restrict__ hhist, const float* __restrict__ W_p,
    const float* __restrict__ b_p, float* __restrict__ out)
{
  const int tid = threadIdx.x;
  const int row = blockIdx.x*4 + (tid>>6);
  const int ln = tid & 63;
  ushort4 hv = ((const ushort4*)(hhist + (size_t)row*256))[ln];
  float4 wp = ((const float4*)W_p)[ln];
  float s = bf2f(hv.x)*wp.x + bf2f(hv.y)*wp.y + bf2f(hv.z)*wp.z + bf2f(hv.w)*wp.w;
  #pragma unroll
  for (int off=32; off; off>>=1) s += __shfl_xor(s, off);
  if (ln == 0) out[row] = sigf(s + b_p[0]);
}

extern "C" void kernel_launch(void* const* d_in, const int* in_sizes, int n_in,
                              void* d_out, int out_size, void* d_ws, size_t ws_size,
                              hipStream_t stream)
{
  const int*   q     = (const int*)d_in[0];
  const int*   r     = (const int*)d_in[1];
  const float* k_emb = (const float*)d_in[2];
  const float* x_emb = (const float*)d_in[3];
  const float* Mk    = (const float*)d_in[4];
  const float* Mv0   = (const float*)d_in[5];
  const float* W_a   = (const float*)d_in[6];
  const float* b_a   = (const float*)d_in[7];
  const float* W_e   = (const float*)d_in[8];
  const float* b_e   = (const float*)d_in[9];
  const float* W_add = (const float*)d_in[10];
  const float* b_add = (const float*)d_in[11];
  const float* W_f   = (const float*)d_in[12];
  const float* b_f   = (const float*)d_in[13];
  const float* hx    = (const float*)d_in[14];
  const float* cx    = (const float*)d_in[15];
  const float* W_ih  = (const float*)d_in[16];
  const float* b_ih  = (const float*)d_in[17];
  const float* W_hh  = (const float*)d_in[18];
  const float* b_hh  = (const float*)d_in[19];
  const float* W_p   = (const float*)d_in[20];
  const float* b_p   = (const float*)d_in[21];
  float* out = (float*)d_out;

  // byte-offset workspace layout
  char* base = (char*)d_ws;
  float*  vbuf  = (float*)(base);                          // 13.1MB
  ushort* webuf = (ushort*)(base + 13107200);              // 6.55MB
  float*  ebuf  = (float*)(base + 19660800);               // 13.1MB
  float*  abuf  = (float*)(base + 32768000);               // 13.1MB
  float*  X2    = (float*)(base + 45875200);               // 26.2MB [reads|k]
  float*  wbuf  = (float*)(base + 72089600);               // 3.3MB
  ushort* fbuf  = (ushort*)(base + 75366400);              // 6.55MB
  ushort* gin2  = (ushort*)(base);                         // 26.2MB overlay (vbuf..ebuf dead)
  short*  hhist = (short*)fbuf;                            // overlay (fbuf dead post-gin)
  unsigned long long* xbuf = (unsigned long long*)(base + 81920000); // 64KB fresh

  k_gather_attn<<<NROWS/4, 256, 0, stream>>>(q, r, k_emb, x_emb, Mk, X2, vbuf, wbuf);
  // we = [k|v] @ W_a^T + b_a  -> bf16
  k_gemm2<0,0,1><<<dim3(NROWS/64, 4), 256, 0, stream>>>(X2+DS, 512, DS, vbuf, DS, DS, W_a, b_a, nullptr, webuf, DS);
  // erase/add fused (A = webuf bf16)
  k_gemm_ea<<<dim3(NROWS/64, 4), 256, 0, stream>>>(webuf, W_e, b_e, W_add, b_add, ebuf, abuf);
  // memory scan -> reads into X2[:,0:256]
  k_scan<<<BS, DS, 0, stream>>>(wbuf, ebuf, abuf, Mv0, X2);
  // f = tanh([reads|k] @ W_f^T + b_f) -> bf16
  k_gemm2<2,0,1><<<dim3(NROWS/64, 4), 256, 0, stream>>>(X2, 512, DS, X2+DS, 512, DS, W_f, b_f, nullptr, fbuf, DS);
  // gin = f @ W_ih^T + (b_ih + b_hh) -> bf16 gate-interleaved
  k_gemm2<0,1,2><<<dim3(NROWS/64, 16), 256, 0, stream>>>(fbuf, DS, DS, fbuf, DS, 0, W_ih, b_ih, b_hh, gin2, 1024);
  // pairwise tagged-slot LSTM (R5 structure)
  {
    const ushort* gin_c = gin2;
    void* args[] = { (void*)&gin_c, (void*)&W_hh, (void*)&hx, (void*)&cx,
                     (void*)&hhist, (void*)&xbuf };
    hipLaunchCooperativeKernel((void*)k_lstm2, dim3(LBLK), dim3(512), args, 0, stream);
  }
  // p = sigmoid(h . W_p + b_p)
  k_pout<<<NROWS/4, 256, 0, stream>>>(hhist, W_p, b_p, out);
}